// Round 10
// baseline (250.206 us; speedup 1.0000x reference)
//
#include <hip/hip_runtime.h>
#include <hip/hip_bf16.h>

#define SDIM 2048
#define BATCH 4
#define DMODEL 512
#define NH 8
#define NKV 2
#define HD 64

typedef __bf16 bf16x8 __attribute__((ext_vector_type(8)));
typedef float floatx16 __attribute__((ext_vector_type(16)));
typedef unsigned short u16;
typedef unsigned int u32;

#define MFMA32 __builtin_amdgcn_mfma_f32_32x32x16_bf16
#define ZERO16 {0.f,0.f,0.f,0.f,0.f,0.f,0.f,0.f,0.f,0.f,0.f,0.f,0.f,0.f,0.f,0.f}
// softmax scale with log2(e) folded: exp(s*0.125) = exp2(s*0.125*log2e)
#define QSCALE 0.18033688011112042f

__device__ __forceinline__ u16 f2bf(float f) {
  union { float f; u32 u; } a; a.f = f;
  u32 r = a.u + 0x7fffu + ((a.u >> 16) & 1u);
  return (u16)(r >> 16);
}
__device__ __forceinline__ u32 pkbf(float lo, float hi) {
  __hip_bfloat162 h = __float22bfloat162_rn(float2{lo, hi});
  union { __hip_bfloat162 h; u32 u; } c; c.h = h;
  return c.u;
}

// ---- fused conversions: x fp32->bf16 (blocks 0..4095), weights -> WT[1280][512] ----
__global__ __launch_bounds__(256) void cvt_kernel(const float* __restrict__ x,
                                                  const float* __restrict__ Wq,
                                                  const float* __restrict__ Wk,
                                                  const float* __restrict__ Wv,
                                                  const float* __restrict__ Wo,
                                                  u16* __restrict__ xb,
                                                  u16* __restrict__ WT) {
  int bid = blockIdx.x;
  if (bid < 4096) {
    int i = bid * 256 + threadIdx.x;
    float4 v = reinterpret_cast<const float4*>(x)[i];
    uint2 o = {pkbf(v.x, v.y), pkbf(v.z, v.w)};
    reinterpret_cast<uint2*>(xb)[i] = o;
  } else {
    int i = (bid - 4096) * 256 + threadIdx.x;  // < 1280*512
    int n = i >> 9, k = i & 511;
    float v;
    if (n < 512)       v = Wq[k * 512 + n];
    else if (n < 640)  v = Wk[k * 128 + (n - 512)];
    else if (n < 768)  v = Wv[k * 128 + (n - 640)];
    else               v = Wo[k * 512 + (n - 768)];
    WT[i] = f2bf(v);
  }
}

// ---- fused QKV projection: 128x128 block tile, BK=32, wave = 64m x 64n (4 MFMAs
// per 4 LDS frag reads), dist-2 register prefetch, LDS dbuf stride-40.
// B LDS rows even/odd interleaved: row rb -> col n0 + 64*(rb>>6) + 2*(rb&31) + ((rb>>5)&1)
// so wave N-tiles pair adjacent cols -> packed u32 / transposed-V epilogues.
__global__ __launch_bounds__(256, 3) void gemm_qkv_kernel(const u16* __restrict__ A,
                                                          const u16* __restrict__ WT,
                                                          const float* __restrict__ bq,
                                                          const float* __restrict__ bk,
                                                          const float* __restrict__ bv,
                                                          u16* __restrict__ Qb,
                                                          u16* __restrict__ Kb,
                                                          u16* __restrict__ Vt) {
  __shared__ __align__(16) u16 abuf[2][128 * 40];
  __shared__ __align__(16) u16 bbuf[2][128 * 40];
  int tid = threadIdx.x;
  int lane = tid & 63, wave = tid >> 6;
  int l31 = lane & 31, half = lane >> 5;
  int m0 = blockIdx.y * 128, n0 = blockIdx.x * 128;
  int ra = tid >> 2, ch = tid & 3;
  // staging rows ra, ra+64
  int c_lo = n0 + 2 * (ra & 31) + ((ra >> 5) & 1);  // interleaved col for B row ra
  const u16* As0 = A + (size_t)(m0 + ra) * DMODEL + ch * 8;
  const u16* As1 = As0 + (size_t)64 * DMODEL;
  const u16* Bs0 = WT + (size_t)c_lo * DMODEL + ch * 8;
  const u16* Bs1 = Bs0 + (size_t)64 * DMODEL;  // col c_lo + 64
  int wo = ra * 40 + ch * 8, wo1 = wo + 64 * 40;

  bf16x8 rA0[2], rA1[2], rB0[2], rB1[2];
  rA0[0] = *(const bf16x8*)As0;        rA1[0] = *(const bf16x8*)As1;
  rB0[0] = *(const bf16x8*)Bs0;        rB1[0] = *(const bf16x8*)Bs1;
  rA0[1] = *(const bf16x8*)(As0 + 32); rA1[1] = *(const bf16x8*)(As1 + 32);
  rB0[1] = *(const bf16x8*)(Bs0 + 32); rB1[1] = *(const bf16x8*)(Bs1 + 32);
  *(bf16x8*)(abuf[0] + wo) = rA0[0];   *(bf16x8*)(abuf[0] + wo1) = rA1[0];
  *(bf16x8*)(bbuf[0] + wo) = rB0[0];   *(bf16x8*)(bbuf[0] + wo1) = rB1[0];
  __syncthreads();

  floatx16 a00 = ZERO16, a01 = ZERO16, a10 = ZERO16, a11 = ZERO16;
  int mh = (wave & 1) * 64, nh = (wave >> 1) * 64;
  for (int it = 0; it < 16; ++it) {
    if (it < 14) {
      rA0[it & 1] = *(const bf16x8*)(As0 + (it + 2) * 32);
      rA1[it & 1] = *(const bf16x8*)(As1 + (it + 2) * 32);
      rB0[it & 1] = *(const bf16x8*)(Bs0 + (it + 2) * 32);
      rB1[it & 1] = *(const bf16x8*)(Bs1 + (it + 2) * 32);
    }
    const u16* ab = abuf[it & 1];
    const u16* bb = bbuf[it & 1];
#pragma unroll
    for (int ks = 0; ks < 2; ++ks) {
      int co = (2 * ks + half) * 8;
      bf16x8 af0 = *(const bf16x8*)(ab + (mh + l31) * 40 + co);
      bf16x8 af1 = *(const bf16x8*)(ab + (mh + 32 + l31) * 40 + co);
      bf16x8 bf0 = *(const bf16x8*)(bb + (nh + l31) * 40 + co);
      bf16x8 bf1 = *(const bf16x8*)(bb + (nh + 32 + l31) * 40 + co);
      a00 = MFMA32(af0, bf0, a00, 0, 0, 0);
      a01 = MFMA32(af0, bf1, a01, 0, 0, 0);
      a10 = MFMA32(af1, bf0, a10, 0, 0, 0);
      a11 = MFMA32(af1, bf1, a11, 0, 0, 0);
    }
    if (it < 15) {
      int nx = (it + 1) & 1;
      *(bf16x8*)(abuf[nx] + wo) = rA0[nx];  *(bf16x8*)(abuf[nx] + wo1) = rA1[nx];
      *(bf16x8*)(bbuf[nx] + wo) = rB0[nx];  *(bf16x8*)(bbuf[nx] + wo1) = rB1[nx];
    }
    __syncthreads();
  }

  int c0 = n0 + nh + 2 * l31;   // even col; odd = c0+1
  int b4 = m0 >> 11;
  if (c0 >= 640) {
    // V transposed epilogue: Vt[b,kv,d,s]
    int lc = c0 - 640;
    float bl0 = bv[lc], bl1 = bv[lc + 1];
    int hkv = lc >> 6, d = lc & 63;
    u16* vr0 = Vt + ((size_t)(b4 * NKV + hkv) * HD + d) * SDIM;
    u16* vr1 = vr0 + SDIM;
#pragma unroll
    for (int mt = 0; mt < 2; ++mt) {
      const floatx16& ae = mt ? a10 : a00;
      const floatx16& ao = mt ? a11 : a01;
#pragma unroll
      for (int g = 0; g < 4; ++g) {
        int s = (m0 + mh + mt * 32 + 8 * g + 4 * half) & 2047;
        ushort4 t0, t1;
        t0.x = f2bf(ae[4*g+0] + bl0); t0.y = f2bf(ae[4*g+1] + bl0);
        t0.z = f2bf(ae[4*g+2] + bl0); t0.w = f2bf(ae[4*g+3] + bl0);
        t1.x = f2bf(ao[4*g+0] + bl1); t1.y = f2bf(ao[4*g+1] + bl1);
        t1.z = f2bf(ao[4*g+2] + bl1); t1.w = f2bf(ao[4*g+3] + bl1);
        *(ushort4*)(vr0 + s) = t0;
        *(ushort4*)(vr1 + s) = t1;
      }
    }
  } else {
    u16* outp; const float* bias; float scale; int nhreg, lc;
    if (c0 < 512) { outp = Qb; bias = bq; scale = QSCALE; nhreg = NH;  lc = c0; }
    else          { outp = Kb; bias = bk; scale = 1.0f;   nhreg = NKV; lc = c0 - 512; }
    float bl0 = bias[lc], bl1 = bias[lc + 1];
    int h2 = lc >> 6, d = lc & 63;
    u32* base = (u32*)(outp + ((size_t)(b4 * nhreg + h2) * SDIM) * HD + d);
#pragma unroll
    for (int mt = 0; mt < 2; ++mt) {
      const floatx16& ae = mt ? a10 : a00;
      const floatx16& ao = mt ? a11 : a01;
#pragma unroll
      for (int r = 0; r < 16; ++r) {
        int s = (m0 + mh + mt * 32 + (r & 3) + 8 * (r >> 2) + 4 * half) & 2047;
        base[(size_t)s * 32] = pkbf((ae[r] + bl0) * scale, (ao[r] + bl1) * scale);
      }
    }
  }
}

// ---- O projection: 128x128 tile, same pipeline, fp32 float2 epilogue ----
__global__ __launch_bounds__(256, 3) void gemm_out_kernel(const u16* __restrict__ A,
                                                          const u16* __restrict__ WTo,
                                                          const float* __restrict__ bo,
                                                          float* __restrict__ out) {
  __shared__ __align__(16) u16 abuf[2][128 * 40];
  __shared__ __align__(16) u16 bbuf[2][128 * 40];
  int tid = threadIdx.x;
  int lane = tid & 63, wave = tid >> 6;
  int l31 = lane & 31, half = lane >> 5;
  int m0 = blockIdx.y * 128, n0 = blockIdx.x * 128;
  int ra = tid >> 2, ch = tid & 3;
  int c_lo = n0 + 2 * (ra & 31) + ((ra >> 5) & 1);
  const u16* As0 = A + (size_t)(m0 + ra) * DMODEL + ch * 8;
  const u16* As1 = As0 + (size_t)64 * DMODEL;
  const u16* Bs0 = WTo + (size_t)c_lo * DMODEL + ch * 8;
  const u16* Bs1 = Bs0 + (size_t)64 * DMODEL;
  int wo = ra * 40 + ch * 8, wo1 = wo + 64 * 40;

  bf16x8 rA0[2], rA1[2], rB0[2], rB1[2];
  rA0[0] = *(const bf16x8*)As0;        rA1[0] = *(const bf16x8*)As1;
  rB0[0] = *(const bf16x8*)Bs0;        rB1[0] = *(const bf16x8*)Bs1;
  rA0[1] = *(const bf16x8*)(As0 + 32); rA1[1] = *(const bf16x8*)(As1 + 32);
  rB0[1] = *(const bf16x8*)(Bs0 + 32); rB1[1] = *(const bf16x8*)(Bs1 + 32);
  *(bf16x8*)(abuf[0] + wo) = rA0[0];   *(bf16x8*)(abuf[0] + wo1) = rA1[0];
  *(bf16x8*)(bbuf[0] + wo) = rB0[0];   *(bf16x8*)(bbuf[0] + wo1) = rB1[0];
  __syncthreads();

  floatx16 a00 = ZERO16, a01 = ZERO16, a10 = ZERO16, a11 = ZERO16;
  int mh = (wave & 1) * 64, nh = (wave >> 1) * 64;
  for (int it = 0; it < 16; ++it) {
    if (it < 14) {
      rA0[it & 1] = *(const bf16x8*)(As0 + (it + 2) * 32);
      rA1[it & 1] = *(const bf16x8*)(As1 + (it + 2) * 32);
      rB0[it & 1] = *(const bf16x8*)(Bs0 + (it + 2) * 32);
      rB1[it & 1] = *(const bf16x8*)(Bs1 + (it + 2) * 32);
    }
    const u16* ab = abuf[it & 1];
    const u16* bb = bbuf[it & 1];
#pragma unroll
    for (int ks = 0; ks < 2; ++ks) {
      int co = (2 * ks + half) * 8;
      bf16x8 af0 = *(const bf16x8*)(ab + (mh + l31) * 40 + co);
      bf16x8 af1 = *(const bf16x8*)(ab + (mh + 32 + l31) * 40 + co);
      bf16x8 bf0 = *(const bf16x8*)(bb + (nh + l31) * 40 + co);
      bf16x8 bf1 = *(const bf16x8*)(bb + (nh + 32 + l31) * 40 + co);
      a00 = MFMA32(af0, bf0, a00, 0, 0, 0);
      a01 = MFMA32(af0, bf1, a01, 0, 0, 0);
      a10 = MFMA32(af1, bf0, a10, 0, 0, 0);
      a11 = MFMA32(af1, bf1, a11, 0, 0, 0);
    }
    if (it < 15) {
      int nx = (it + 1) & 1;
      *(bf16x8*)(abuf[nx] + wo) = rA0[nx];  *(bf16x8*)(abuf[nx] + wo1) = rA1[nx];
      *(bf16x8*)(bbuf[nx] + wo) = rB0[nx];  *(bf16x8*)(bbuf[nx] + wo1) = rB1[nx];
    }
    __syncthreads();
  }

  int n = n0 + nh + 2 * l31;
  float bl0 = bo[n], bl1 = bo[n + 1];
#pragma unroll
  for (int mt = 0; mt < 2; ++mt) {
    const floatx16& ae = mt ? a10 : a00;
    const floatx16& ao = mt ? a11 : a01;
#pragma unroll
    for (int r = 0; r < 16; ++r) {
      int m = m0 + mh + mt * 32 + (r & 3) + 8 * (r >> 2) + 4 * half;
      *(float2*)(out + (size_t)m * DMODEL + n) = float2{ae[r] + bl0, ao[r] + bl1};
    }
  }
}

// ---- flash attention, S^T formulation, 64 q per wave (each K/V frag feeds 2 MFMAs):
// block = 4 waves = 128 q x keysplit 2 (pair p owns 1024 keys). 16 iters x 64 keys.
// LDS: smem[4][64*72] = K/V tiles per pair (36 KB), single-buffered 2-barrier,
// register prefetch. No-max softmax via v_exp2; P^T built in regs via shfl_xor(32).
__global__ __launch_bounds__(256, 2) void attn_kernel(const u16* __restrict__ Q,
                                                      const u16* __restrict__ K,
                                                      const u16* __restrict__ Vt,
                                                      u16* __restrict__ O) {
  __shared__ __align__(16) u16 smem[4][64 * 72];  // [p] = K, [2+p] = V
  int tid = threadIdx.x;
  int lane = tid & 63, w = tid >> 6;
  int l31 = lane & 31, half = lane >> 5;
  int sgr = w & 1, p = w >> 1;
  int bh = blockIdx.y;
  int b = bh >> 3, h = bh & 7, kv = h >> 2;
  int q0 = blockIdx.x * 128;
  const u16* Qh = Q + (size_t)(b * NH + h) * SDIM * HD;
  const u16* Kh = K + (size_t)(b * NKV + kv) * SDIM * HD + (size_t)p * 1024 * HD;
  const u16* Vh = Vt + (size_t)(b * NKV + kv) * HD * SDIM + p * 1024;

  // Q B-frags for 2 q-tiles (held in regs)
  bf16x8 qb0[4], qb1[4];
#pragma unroll
  for (int ks = 0; ks < 4; ++ks) {
    qb0[ks] = *(const bf16x8*)(Qh + (size_t)(q0 + sgr * 64 + l31) * HD + ks * 16 + half * 8);
    qb1[ks] = *(const bf16x8*)(Qh + (size_t)(q0 + sgr * 64 + 32 + l31) * HD + ks * 16 + half * 8);
  }

  // staging (per pair, 128 threads): K rows=keys natural; V rows rv<32 -> d=2rv, rv>=32 -> odd
  int ptid = tid & 127;
  int rr = ptid >> 3, ch = ptid & 7;  // rr 0..15
  const u16* K0 = Kh + (size_t)rr * HD + ch * 8;
  const u16* V0 = Vh + (size_t)(2 * rr) * SDIM + ch * 8;
  int w0 = rr * 72 + ch * 8;
  u16* kbp = smem[p];
  u16* vbp = smem[2 + p];

  bf16x8 sK0 = *(const bf16x8*)(K0);
  bf16x8 sK1 = *(const bf16x8*)(K0 + 1024);
  bf16x8 sK2 = *(const bf16x8*)(K0 + 2048);
  bf16x8 sK3 = *(const bf16x8*)(K0 + 3072);
  bf16x8 sV0 = *(const bf16x8*)(V0);
  bf16x8 sV1 = *(const bf16x8*)(V0 + (size_t)32 * SDIM);
  bf16x8 sV2 = *(const bf16x8*)(V0 + (size_t)1 * SDIM);
  bf16x8 sV3 = *(const bf16x8*)(V0 + (size_t)33 * SDIM);
  *(bf16x8*)(kbp + w0) = sK0;           *(bf16x8*)(kbp + w0 + 1152) = sK1;
  *(bf16x8*)(kbp + w0 + 2304) = sK2;    *(bf16x8*)(kbp + w0 + 3456) = sK3;
  *(bf16x8*)(vbp + w0) = sV0;           *(bf16x8*)(vbp + w0 + 1152) = sV1;
  *(bf16x8*)(vbp + w0 + 2304) = sV2;    *(bf16x8*)(vbp + w0 + 3456) = sV3;
  __syncthreads();

  floatx16 o00 = ZERO16, o01 = ZERO16, o10 = ZERO16, o11 = ZERO16;  // [qt][even/odd d]
  float sm0 = 0.0f, sm1 = 0.0f;

  for (int it = 0; it < 16; ++it) {
    if (it < 15) {
      const u16* Kn = K0 + (it + 1) * 4096;
      sK0 = *(const bf16x8*)(Kn);
      sK1 = *(const bf16x8*)(Kn + 1024);
      sK2 = *(const bf16x8*)(Kn + 2048);
      sK3 = *(const bf16x8*)(Kn + 3072);
      const u16* Vn = V0 + (it + 1) * 64;
      sV0 = *(const bf16x8*)(Vn);
      sV1 = *(const bf16x8*)(Vn + (size_t)32 * SDIM);
      sV2 = *(const bf16x8*)(Vn + (size_t)1 * SDIM);
      sV3 = *(const bf16x8*)(Vn + (size_t)33 * SDIM);
    }

#pragma unroll
    for (int seg = 0; seg < 2; ++seg) {
      floatx16 sa0 = ZERO16, sa1 = ZERO16;
#pragma unroll
      for (int ks = 0; ks < 4; ++ks) {
        bf16x8 kf = *(const bf16x8*)(kbp + (seg * 32 + l31) * 72 + ks * 16 + half * 8);
        sa0 = MFMA32(kf, qb0[ks], sa0, 0, 0, 0);
        sa1 = MFMA32(kf, qb1[ks], sa1, 0, 0, 0);
      }
      float pa0[16], pa1[16];
#pragma unroll
      for (int r = 0; r < 16; ++r) {
        pa0[r] = __builtin_amdgcn_exp2f(sa0[r]); sm0 += pa0[r];
        pa1[r] = __builtin_amdgcn_exp2f(sa1[r]); sm1 += pa1[r];
      }
#pragma unroll
      for (int kc = 0; kc < 2; ++kc) {
        int co = (seg * 2 + kc) * 16 + half * 8;
        bf16x8 vf0 = *(const bf16x8*)(vbp + l31 * 72 + co);
        bf16x8 vf1 = *(const bf16x8*)(vbp + (32 + l31) * 72 + co);
        // build P^T B-frags for both q-tiles via half-exchange
        union { uint4 u; bf16x8 v; } pf0, pf1;
        {
          u32 a0 = pkbf(pa0[8*kc+0], pa0[8*kc+1]);
          u32 a1 = pkbf(pa0[8*kc+2], pa0[8*kc+3]);
          u32 b0 = pkbf(pa0[8*kc+4], pa0[8*kc+5]);
          u32 b1 = pkbf(pa0[8*kc+6], pa0[8*kc+7]);
          u32 r0 = (u32)__shfl_xor((int)(half ? a0 : b0), 32);
          u32 r1 = (u32)__shfl_xor((int)(half ? a1 : b1), 32);
          pf0.u.x = half ? r0 : a0;  pf0.u.y = half ? r1 : a1;
          pf0.u.z = half ? b0 : r0;  pf0.u.w = half ? b1 : r1;
        }
        {
          u32 a0 = pkbf(pa1[8*kc+0], pa1[8*kc+1]);
          u32 a1 = pkbf(pa1[8*kc+2], pa1[8*kc+3]);
          u32 b0 = pkbf(pa1[8*kc+4], pa1[8*kc+5]);
          u32 b1 = pkbf(pa1[8*kc+6], pa1[8*kc+7]);
          u32 r0 = (u32)__shfl_xor((int)(half ? a0 : b0), 32);
          u32 r1 = (u32)__shfl_xor((int)(half ? a1 : b1), 32);
          pf1.u.x = half ? r0 : a0;  pf1.u.y = half ? r1 : a1;
          pf1.u.z = half ? b0 : r0;  pf1.u.w = half ? b1 : r1;
        }
        o00 = MFMA32(vf0, pf0.v, o00, 0, 0, 0);
        o01 = MFMA32(vf1, pf0.v, o01, 0, 0, 0);
        o10 = MFMA32(vf0, pf1.v, o10, 0, 0, 0);
        o11 = MFMA32(vf1, pf1.v, o11, 0, 0, 0);
      }
    }

    __syncthreads();
    if (it < 15) {
      *(bf16x8*)(kbp + w0) = sK0;           *(bf16x8*)(kbp + w0 + 1152) = sK1;
      *(bf16x8*)(kbp + w0 + 2304) = sK2;    *(bf16x8*)(kbp + w0 + 3456) = sK3;
      *(bf16x8*)(vbp + w0) = sV0;           *(bf16x8*)(vbp + w0 + 1152) = sV1;
      *(bf16x8*)(vbp + w0 + 2304) = sV2;    *(bf16x8*)(vbp + w0 + 3456) = sV3;
    }
    __syncthreads();
  }

  sm0 += __shfl_xor(sm0, 32);
  sm1 += __shfl_xor(sm1, 32);

  // cross-pair merge via LDS: 256 slots (s,qt,half,l31) x 36 floats = 36864 B
  __syncthreads();
  float* cmb = (float*)smem;
  int slot0 = (((sgr * 2 + 0) * 2 + half) * 32 + l31) * 36;
  int slot1 = (((sgr * 2 + 1) * 2 + half) * 32 + l31) * 36;
  if (p == 1) {
#pragma unroll
    for (int g = 0; g < 4; ++g) {
      *(float4*)(cmb + slot0 + 4*g)      = float4{o00[4*g], o00[4*g+1], o00[4*g+2], o00[4*g+3]};
      *(float4*)(cmb + slot0 + 16 + 4*g) = float4{o01[4*g], o01[4*g+1], o01[4*g+2], o01[4*g+3]};
      *(float4*)(cmb + slot1 + 4*g)      = float4{o10[4*g], o10[4*g+1], o10[4*g+2], o10[4*g+3]};
      *(float4*)(cmb + slot1 + 16 + 4*g) = float4{o11[4*g], o11[4*g+1], o11[4*g+2], o11[4*g+3]};
    }
    cmb[slot0 + 32] = sm0;
    cmb[slot1 + 32] = sm1;
  }
  __syncthreads();
  if (p == 0) {
#pragma unroll
    for (int qt = 0; qt < 2; ++qt) {
      floatx16& oe = qt ? o10 : o00;
      floatx16& oo = qt ? o11 : o01;
      int slot = qt ? slot1 : slot0;
#pragma unroll
      for (int g = 0; g < 4; ++g) {
        float4 ae = *(const float4*)(cmb + slot + 4*g);
        float4 ao = *(const float4*)(cmb + slot + 16 + 4*g);
        oe[4*g] += ae.x; oe[4*g+1] += ae.y; oe[4*g+2] += ae.z; oe[4*g+3] += ae.w;
        oo[4*g] += ao.x; oo[4*g+1] += ao.y; oo[4*g+2] += ao.z; oo[4*g+3] += ao.w;
      }
      float inv = 1.0f / ((qt ? sm1 : sm0) + cmb[slot + 32]);
      int q = q0 + sgr * 64 + qt * 32 + l31;
      u32* dst = (u32*)O + (((size_t)(b * SDIM + q)) * DMODEL + h * HD) / 2;
#pragma unroll
      for (int g = 0; g < 4; ++g) {
        uint4 t;
        t.x = pkbf(oe[4*g+0] * inv, oo[4*g+0] * inv);
        t.y = pkbf(oe[4*g+1] * inv, oo[4*g+1] * inv);
        t.z = pkbf(oe[4*g+2] * inv, oo[4*g+2] * inv);
        t.w = pkbf(oe[4*g+3] * inv, oo[4*g+3] * inv);
        *(uint4*)(dst + 8 * g + 4 * half) = t;
      }
    }
  }
}

extern "C" void kernel_launch(void* const* d_in, const int* in_sizes, int n_in,
                              void* d_out, int out_size, void* d_ws, size_t ws_size,
                              hipStream_t stream) {
  const float* x  = (const float*)d_in[0];
  const float* Wq = (const float*)d_in[1];
  const float* bq = (const float*)d_in[2];
  const float* Wk = (const float*)d_in[3];
  const float* bk = (const float*)d_in[4];
  const float* Wv = (const float*)d_in[5];
  const float* bv = (const float*)d_in[6];
  const float* Wo = (const float*)d_in[7];
  const float* bo = (const float*)d_in[8];
  float* out = (float*)d_out;

  const size_t M = (size_t)BATCH * SDIM;  // 8192
  u16* xb  = (u16*)d_ws;                  // 8192*512
  u16* WT  = xb  + M * DMODEL;            // 1280*512
  u16* Qb  = WT  + 1280 * DMODEL;         // 8192*512  [B,NH,S,64]
  u16* Kb  = Qb  + M * DMODEL;            // 8192*128  [B,NKV,S,64]
  u16* VtB = Kb  + M * 128;               // 8192*128  [B,NKV,64,S]
  u16* Ab  = VtB + M * 128;               // 8192*512  [B,S,512]

  cvt_kernel<<<4096 + 2560, 256, 0, stream>>>(x, Wq, Wk, Wv, Wo, xb, WT);
  gemm_qkv_kernel<<<dim3(768 / 128, M / 128), 256, 0, stream>>>(xb, WT, bq, bk, bv, Qb, Kb, VtB);
  attn_kernel<<<dim3(SDIM / 128, BATCH * NH), 256, 0, stream>>>(Qb, Kb, VtB, Ab);
  gemm_out_kernel<<<dim3(512 / 128, M / 128), 256, 0, stream>>>(Ab, WT + (size_t)768 * DMODEL, bo, out);
}